// Round 14
// baseline (413.788 us; speedup 1.0000x reference)
//
#include <hip/hip_runtime.h>

typedef unsigned short u16;
typedef unsigned int u32;
typedef __attribute__((ext_vector_type(8))) __bf16 bf16x8;
typedef __attribute__((ext_vector_type(2))) __bf16 bf16x2;
typedef __attribute__((ext_vector_type(4))) float f32x4;
typedef __attribute__((ext_vector_type(16))) float f32x16;
typedef __attribute__((ext_vector_type(4))) u32 u32x4;

__device__ inline u16 f2bf(float f) {
  unsigned u = __builtin_bit_cast(unsigned, f);
  u += 0x7FFFu + ((u >> 16) & 1u);
  return (u16)(u >> 16);
}

__device__ inline u32 packbf(float a, float b) {
  bf16x2 t;
  t[0] = (__bf16)a;
  t[1] = (__bf16)b;
  return __builtin_bit_cast(u32, t);
}

__device__ inline void async16(const void* g, void* l) {
  __builtin_amdgcn_global_load_lds((const __attribute__((address_space(1))) void*)g,
                                   (__attribute__((address_space(3))) void*)l, 16, 0, 0);
}

// ---------------- x fp32 -> bf16 ----------------
__global__ __launch_bounds__(256) void xconv(const float* __restrict__ x, u16* __restrict__ xb) {
  int i = blockIdx.x * 256 + threadIdx.x;
  float4 v = ((const float4*)x)[i];
  ushort4 r;
  r.x = f2bf(v.x); r.y = f2bf(v.y); r.z = f2bf(v.z); r.w = f2bf(v.w);
  ((ushort4*)xb)[i] = r;
}

// ---------------- all 4 weights: W (d,e) fp32 -> Wt (e,d) bf16, one launch ----------------
// z==0 (W_Q) folds 0.125*log2(e) so QK^T comes out in exp2 domain.
__global__ __launch_bounds__(256) void wtrans4(const float* __restrict__ W0,
                                               const float* __restrict__ W1,
                                               const float* __restrict__ W2,
                                               const float* __restrict__ W3,
                                               u16* __restrict__ WtQKV,
                                               u16* __restrict__ WtO) {
  __shared__ u16 tile[32][33];
  const int z = blockIdx.z;
  const float* W = (z == 0) ? W0 : (z == 1) ? W1 : (z == 2) ? W2 : W3;
  u16* Wt = (z < 3) ? (WtQKV + (size_t)z * 1024 * 1024) : WtO;
  const float s = (z == 0) ? 0.18033688011112042f : 1.0f;
  const int e0 = blockIdx.x * 32;
  const int d0 = blockIdx.y * 32;
  const int tx = threadIdx.x & 31;
  const int ty = threadIdx.x >> 5;
#pragma unroll
  for (int i = ty; i < 32; i += 8)
    tile[i][tx] = f2bf(W[(size_t)(d0 + i) * 1024 + e0 + tx] * s);
  __syncthreads();
#pragma unroll
  for (int i = ty; i < 32; i += 8)
    Wt[(size_t)(e0 + i) * 1024 + d0 + tx] = tile[tx][i];
}

// ---------------- V slice of QKV -> Vtg[b*1024+dg][s] (transposed) ----------------
__global__ __launch_bounds__(256) void vtrans(const u16* __restrict__ QKV, u16* __restrict__ Vtg) {
  __shared__ u16 t[32][66];
  const int tid = threadIdx.x;
  const int s0 = blockIdx.x * 32, dg0 = blockIdx.y * 64, b = blockIdx.z;
  {
    const int i = tid >> 3, c = (tid & 7) * 8;
    uint4 v = *(const uint4*)(QKV + (size_t)(b * 2048 + s0 + i) * 3072 + 2048 + dg0 + c);
    u16 tmp[8];
    *(uint4*)tmp = v;
#pragma unroll
    for (int e = 0; e < 8; ++e) t[i][c + e] = tmp[e];
  }
  __syncthreads();
  {
    const int r = tid >> 2, cg = (tid & 3) * 8;
    u16 tmp[8];
#pragma unroll
    for (int e = 0; e < 8; ++e) tmp[e] = t[cg + e][r];
    *(uint4*)(Vtg + (size_t)(b * 1024 + dg0 + r) * 2048 + s0 + cg) = *(uint4*)tmp;
  }
}

// ---------------- GEMM C[M,N] = A[M,K] * Bt[N,K]^T  (m97 structure) ----------------
template <int OUT_BF16>
__global__ __launch_bounds__(256) void gemm_bt(const u16* __restrict__ A,
                                               const u16* __restrict__ Bt,
                                               void* __restrict__ Cp,
                                               int M, int N, int K) {
  __shared__ __align__(16) u16 As[128 * 32];
  __shared__ __align__(16) u16 Bs[128 * 32];
  const int tid = threadIdx.x;
  const int lane = tid & 63;
  const int wave = tid >> 6;
  const int lr = lane & 15;
  const int lk = (lane >> 4) * 8;
  const int wm = (wave >> 1) * 64;
  const int wn = (wave & 1) * 64;
  const int bm = blockIdx.x * 128;
  const int bn = blockIdx.y * 128;
  const int srow = lane >> 2;
  const int scol = (lane & 3) * 8;

  f32x4 acc[4][4] = {};

  for (int k0 = 0; k0 < K; k0 += 32) {
#pragma unroll
    for (int r = 0; r < 2; ++r) {
      const int chunk = r * 4 + wave;
      const int row = chunk * 16 + srow;
      async16(A + (size_t)(bm + row) * K + k0 + scol, &As[chunk * 512 + lane * 8]);
      async16(Bt + (size_t)(bn + row) * K + k0 + scol, &Bs[chunk * 512 + lane * 8]);
    }
    __syncthreads();
    bf16x8 a[4], b[4];
#pragma unroll
    for (int i = 0; i < 4; ++i) {
      a[i] = *(const bf16x8*)&As[(wm + i * 16 + lr) * 32 + lk];
      b[i] = *(const bf16x8*)&Bs[(wn + i * 16 + lr) * 32 + lk];
    }
#pragma unroll
    for (int mi = 0; mi < 4; ++mi)
#pragma unroll
      for (int ni = 0; ni < 4; ++ni)
        acc[mi][ni] = __builtin_amdgcn_mfma_f32_16x16x32_bf16(a[mi], b[ni], acc[mi][ni], 0, 0, 0);
    __syncthreads();
  }

#pragma unroll
  for (int mi = 0; mi < 4; ++mi) {
#pragma unroll
    for (int ni = 0; ni < 4; ++ni) {
      const int col = bn + wn + ni * 16 + lr;
#pragma unroll
      for (int j = 0; j < 4; ++j) {
        const int row = bm + wm + mi * 16 + (lane >> 4) * 4 + j;
        if (OUT_BF16)
          ((u16*)Cp)[(size_t)row * N + col] = f2bf(acc[mi][ni][j]);
        else
          ((float*)Cp)[(size_t)row * N + col] = acc[mi][ni][j];
      }
    }
  }
}

// ---------------- Flash causal attention: 64 q/wave, V global->reg, K LDS-staged ----------------
// R13 minus V-in-LDS: V^T fragments load straight from global (L1-resident 8KB/tile, shared
// by all 4 waves), prefetched one iteration ahead into registers. Removes V ds_reads, halves
// staging, LDS 32->16KB. K stays LDS-staged (counted vmcnt(10): K-stage 2 + V-loads 8 issued
// per iteration, pinned by sched_barrier before the wait; prefetch never drained mid-flight).
__global__ __launch_bounds__(256, 3) void attn_kernel(const u16* __restrict__ QKV,
                                                      const u16* __restrict__ Vtg,
                                                      u16* __restrict__ Opart,
                                                      float* __restrict__ Lpart) {
  constexpr int S = 2048, LD = 3072;
  constexpr float MFIX = 12.0f;
  __shared__ __align__(16) u16 Ks[2][64 * 64];

  const int g = 7 - (blockIdx.x >> 1);   // longest (g=7) first
  const int c = blockIdx.x & 1;
  const int bh = blockIdx.y;
  const int b = bh >> 4, h = bh & 15;
  const int tid = threadIdx.x, lane = tid & 63, w = tid >> 6;  // w = 0..3
  const int l31 = lane & 31, lh = lane >> 5;

  const int qbase = g * 256 + w * 64;    // wave owns 64 q rows (2 q-halves)
  const int ktlast = 4 * g + w;          // diagonal k-tile (same for both q-halves)
  const int ktbeg = c * (2 * g + 2);
  const int ktend = (c + 1) * (2 * g + 2);

  // Q fragments, both q-halves: lane holds Q[q=qbase+qh*32+l31][d = cc*16 + lh*8 + i]
  bf16x8 qf[2][4];
#pragma unroll
  for (int qh = 0; qh < 2; ++qh) {
    const u16* qrow = QKV + (size_t)(b * S + qbase + qh * 32 + l31) * LD + h * 64;
#pragma unroll
    for (int cc = 0; cc < 4; ++cc) qf[qh][cc] = *(const bf16x8*)(qrow + cc * 16 + lh * 8);
  }

  // K staging: 512 16B chunks per 64x64 tile, TWO per thread, pre-swizzled source (rule #21)
  const int c0 = tid, c1 = tid + 256;
  const int r0 = c0 >> 3, x0 = ((c0 & 7) ^ (r0 & 7)) << 3;
  const int r1 = c1 >> 3, x1 = ((c1 & 7) ^ (r1 & 7)) << 3;
  const u16* Kbase = QKV + (size_t)b * S * LD + 1024 + h * 64;
  // V global row bases for this lane (V^T rows d=l31 and d=32+l31)
  const u16* Vr0 = Vtg + (size_t)(bh * 64 + l31) * 2048;
  const u16* Vr1 = Vtg + (size_t)(bh * 64 + 32 + l31) * 2048;

#define STAGEK(buf, kt_)                                                         \
  do {                                                                           \
    async16(Kbase + (size_t)((kt_)*64 + r0) * LD + x0, &Ks[buf][c0 * 8]);        \
    async16(Kbase + (size_t)((kt_)*64 + r1) * LD + x1, &Ks[buf][c1 * 8]);        \
  } while (0)

  // V fragments straight from global: dst[kc] = V^T[d][k = (2kc+lh)*8 .. +7] of tile kt_
#define VLOAD(d0_, d1_, kt_)                                                     \
  do {                                                                           \
    _Pragma("unroll") for (int kc = 0; kc < 4; ++kc) {                           \
      const int ci = 2 * kc + lh;                                                \
      d0_[kc] = *(const bf16x8*)(Vr0 + (kt_)*64 + ci * 8);                       \
      d1_[kc] = *(const bf16x8*)(Vr1 + (kt_)*64 + ci * 8);                       \
    }                                                                            \
  } while (0)

  // o[qhalf][dhalf]
  f32x16 o00 = {}, o01 = {}, o10 = {}, o11 = {};
  float l0 = 0.f, l1 = 0.f;

#define TREE16(dst, arr)                                                         \
  do {                                                                           \
    float v_[16];                                                                \
    _Pragma("unroll") for (int r_ = 0; r_ < 16; ++r_) v_[r_] = (arr)[r_];        \
    _Pragma("unroll") for (int s_ = 8; s_ >= 1; s_ >>= 1)                        \
      _Pragma("unroll") for (int r_ = 0; r_ < s_; ++r_) v_[r_] += v_[r_ + s_];   \
    dst += v_[0];                                                                \
  } while (0)

  // verified (R9/R13) PV A-fragment construction from packed P words + lane-half swaps
#define MAKE_PA(pa, pk, sw, q4)                                                  \
  bf16x8 pa;                                                                     \
  {                                                                              \
    u32x4 wv_;                                                                   \
    wv_[0] = lh ? (sw)[(q4) + 2] : (pk)[(q4) + 0];                               \
    wv_[1] = lh ? (sw)[(q4) + 3] : (pk)[(q4) + 1];                               \
    wv_[2] = lh ? (pk)[(q4) + 2] : (sw)[(q4) + 0];                               \
    wv_[3] = lh ? (pk)[(q4) + 3] : (sw)[(q4) + 1];                               \
    pa = __builtin_bit_cast(bf16x8, wv_);                                        \
  }

  bf16x8 vc0[4], vc1[4], vn0[4], vn1[4];   // current / next V fragments (registers)

  STAGEK(0, ktbeg);
  VLOAD(vc0, vc1, ktbeg);

  int cur = 0;
  for (int kt = ktbeg; kt < ktend; ++kt) {
    if (kt + 1 < ktend) {
      STAGEK(cur ^ 1, kt + 1);                 // 2 VMEM ops
      VLOAD(vn0, vn1, kt + 1);                 // 8 VMEM ops
      __builtin_amdgcn_sched_barrier(0);       // pin the 10 issues above the wait
      asm volatile("s_waitcnt vmcnt(10)" ::: "memory");  // tile kt's K landed; prefetch in flight
    } else {
      asm volatile("s_waitcnt vmcnt(0)" ::: "memory");
    }
    __builtin_amdgcn_s_barrier();
    __builtin_amdgcn_sched_barrier(0);

    const bool active = (kt <= ktlast);
    if (active) {
      const bool full = (kt < ktlast);   // not the diagonal tile
      const u16* ks = Ks[cur];

      // S^T quadrants t[khalf][qhalf] = K Q^T (exp2-scaled via W_Q folding)
      f32x16 t00 = {}, t10 = {}, t01 = {}, t11 = {};
      __builtin_amdgcn_s_setprio(1);
#pragma unroll
      for (int cc = 0; cc < 4; ++cc) {
        const int ci = 2 * cc + lh;
        const bf16x8 kf0 = *(const bf16x8*)&ks[l31 * 64 + ((ci ^ (l31 & 7)) << 3)];
        const bf16x8 kf1 = *(const bf16x8*)&ks[(32 + l31) * 64 + ((ci ^ (l31 & 7)) << 3)];
        t00 = __builtin_amdgcn_mfma_f32_32x32x16_bf16(kf0, qf[0][cc], t00, 0, 0, 0);
        t01 = __builtin_amdgcn_mfma_f32_32x32x16_bf16(kf0, qf[1][cc], t01, 0, 0, 0);
        if (full) t10 = __builtin_amdgcn_mfma_f32_32x32x16_bf16(kf1, qf[0][cc], t10, 0, 0, 0);
        t11 = __builtin_amdgcn_mfma_f32_32x32x16_bf16(kf1, qf[1][cc], t11, 0, 0, 0);
      }
      __builtin_amdgcn_s_setprio(0);

      // diagonal mask: khalf0 x qhalf0 and khalf1 x qhalf1 share the same relative mask
      if (!full) {
#pragma unroll
        for (int r = 0; r < 16; ++r) {
          const int ko = (r & 3) + 8 * (r >> 2) + 4 * lh;
          if (ko > l31) { t00[r] = -3e38f; t11[r] = -3e38f; }
        }
      }

      u32 pk0[8], pk1[8], sw0[8], sw1[8];

      // ---- khalf0: exp, sum, pack+swap, PV kc=0,1 ----
#pragma unroll
      for (int r = 0; r < 16; ++r) t00[r] = exp2f(t00[r] - MFIX);
#pragma unroll
      for (int r = 0; r < 16; ++r) t01[r] = exp2f(t01[r] - MFIX);
      TREE16(l0, t00);
      TREE16(l1, t01);
#pragma unroll
      for (int j = 0; j < 8; ++j) {
        pk0[j] = packbf(t00[2 * j], t00[2 * j + 1]);
        pk1[j] = packbf(t01[2 * j], t01[2 * j + 1]);
      }
#pragma unroll
      for (int j = 0; j < 8; ++j) {
        sw0[j] = __shfl_xor(pk0[j], 32);
        sw1[j] = __shfl_xor(pk1[j], 32);
      }
      __builtin_amdgcn_s_setprio(1);
#pragma unroll
      for (int kc = 0; kc < 2; ++kc) {
        const int q4 = kc * 4;
        MAKE_PA(pa0, pk0, sw0, q4)
        MAKE_PA(pa1, pk1, sw1, q4)
        o00 = __builtin_amdgcn_mfma_f32_32x32x16_bf16(pa0, vc0[kc], o00, 0, 0, 0);
        o01 = __builtin_amdgcn_mfma_f32_32x32x16_bf16(pa0, vc1[kc], o01, 0, 0, 0);
        o10 = __builtin_amdgcn_mfma_f32_32x32x16_bf16(pa1, vc0[kc], o10, 0, 0, 0);
        o11 = __builtin_amdgcn_mfma_f32_32x32x16_bf16(pa1, vc1[kc], o11, 0, 0, 0);
      }
      __builtin_amdgcn_s_setprio(0);

      // ---- khalf1: exp, sum, pack+swap, PV kc=2,3 (qhalf0 skipped on diagonal) ----
      if (full) {
#pragma unroll
        for (int r = 0; r < 16; ++r) t10[r] = exp2f(t10[r] - MFIX);
        TREE16(l0, t10);
#pragma unroll
        for (int j = 0; j < 8; ++j) pk0[j] = packbf(t10[2 * j], t10[2 * j + 1]);
#pragma unroll
        for (int j = 0; j < 8; ++j) sw0[j] = __shfl_xor(pk0[j], 32);
      }
#pragma unroll
      for (int r = 0; r < 16; ++r) t11[r] = exp2f(t11[r] - MFIX);
      TREE16(l1, t11);
#pragma unroll
      for (int j = 0; j < 8; ++j) pk1[j] = packbf(t11[2 * j], t11[2 * j + 1]);
#pragma unroll
      for (int j = 0; j < 8; ++j) sw1[j] = __shfl_xor(pk1[j], 32);

      __builtin_amdgcn_s_setprio(1);
#pragma unroll
      for (int kc = 0; kc < 2; ++kc) {
        const int q4 = kc * 4;
        MAKE_PA(pa1, pk1, sw1, q4)
        if (full) {
          MAKE_PA(pa0, pk0, sw0, q4)
          o00 = __builtin_amdgcn_mfma_f32_32x32x16_bf16(pa0, vc0[kc + 2], o00, 0, 0, 0);
          o01 = __builtin_amdgcn_mfma_f32_32x32x16_bf16(pa0, vc1[kc + 2], o01, 0, 0, 0);
        }
        o10 = __builtin_amdgcn_mfma_f32_32x32x16_bf16(pa1, vc0[kc + 2], o10, 0, 0, 0);
        o11 = __builtin_amdgcn_mfma_f32_32x32x16_bf16(pa1, vc1[kc + 2], o11, 0, 0, 0);
      }
      __builtin_amdgcn_s_setprio(0);
    }

    // rotate V prefetch regs; WAR fence for Ks buffer swap
#pragma unroll
    for (int kc = 0; kc < 4; ++kc) {
      vc0[kc] = vn0[kc];
      vc1[kc] = vn1[kc];
    }
    asm volatile("s_waitcnt lgkmcnt(0)" ::: "memory");
    __builtin_amdgcn_s_barrier();
    cur ^= 1;
  }
#undef STAGEK
#undef VLOAD
#undef TREE16
#undef MAKE_PA

  // epilogue: store partial O (bf16, unnormalized) and partial l (f32)
  const float l0t = l0 + __shfl_xor(l0, 32);
  const float l1t = l1 + __shfl_xor(l1, 32);
  u16* Oc = Opart + (size_t)c * 4096 * 1024;
#pragma unroll
  for (int r = 0; r < 16; ++r) {
    const int qo = (r & 3) + 8 * (r >> 2) + 4 * lh;
    u16* p0 = Oc + (size_t)(b * S + qbase + qo) * 1024 + h * 64 + l31;
    u16* p1 = p0 + (size_t)32 * 1024;
    p0[0] = f2bf(o00[r]);
    p0[32] = f2bf(o01[r]);
    p1[0] = f2bf(o10[r]);
    p1[32] = f2bf(o11[r]);
  }
  if (lh == 0) {
    Lpart[(size_t)c * 4096 * 16 + (size_t)(b * S + qbase + l31) * 16 + h] = l0t;
    Lpart[(size_t)c * 4096 * 16 + (size_t)(b * S + qbase + 32 + l31) * 16 + h] = l1t;
  }
}

// ---------------- combine partials: Obuf = (O0 + O1) / (l0 + l1) ----------------
__global__ __launch_bounds__(256) void combine(const u16* __restrict__ Opart,
                                               const float* __restrict__ Lpart,
                                               u16* __restrict__ Obuf) {
  const int i = blockIdx.x * 256 + threadIdx.x;   // 524288 threads: 8 cols each
  const int row = i >> 7;
  const int cw = (i & 127) * 8;
  const int h = cw >> 6;
  const float l = Lpart[(size_t)row * 16 + h] + Lpart[(size_t)4096 * 16 + (size_t)row * 16 + h];
  const float inv = 1.0f / l;
  const bf16x8 a = *(const bf16x8*)(Opart + (size_t)row * 1024 + cw);
  const bf16x8 bq = *(const bf16x8*)(Opart + (size_t)4096 * 1024 + (size_t)row * 1024 + cw);
  u16 out[8];
#pragma unroll
  for (int j = 0; j < 8; ++j) out[j] = f2bf(((float)a[j] + (float)bq[j]) * inv);
  *(uint4*)(Obuf + (size_t)row * 1024 + cw) = *(uint4*)out;
}

extern "C" void kernel_launch(void* const* d_in, const int* in_sizes, int n_in,
                              void* d_out, int out_size, void* d_ws, size_t ws_size,
                              hipStream_t stream) {
  const float* x  = (const float*)d_in[0];
  const float* WQ = (const float*)d_in[1];
  const float* WK = (const float*)d_in[2];
  const float* WV = (const float*)d_in[3];
  const float* WO = (const float*)d_in[4];
  float* out = (float*)d_out;

  u16* xb    = (u16*)d_ws;                      // 4096*1024
  u16* WtQKV = xb + (size_t)4096 * 1024;        // 3072*1024
  u16* WtO   = WtQKV + (size_t)3072 * 1024;     // 1024*1024
  u16* QKV   = WtO + (size_t)1024 * 1024;       // 4096*3072
  u16* Obuf  = QKV + (size_t)4096 * 3072;       // 4096*1024
  u16* Vtg   = Obuf + (size_t)4096 * 1024;      // 2048*2048
  u16* Opart = Vtg + (size_t)2048 * 2048;       // 2 * 4096*1024 bf16
  float* Lpart = (float*)(Opart + (size_t)2 * 4096 * 1024);  // 2 * 4096*16 f32

  xconv<<<4096, 256, 0, stream>>>(x, xb);
  wtrans4<<<dim3(32, 32, 4), 256, 0, stream>>>(WQ, WK, WV, WO, WtQKV, WtO);

  gemm_bt<1><<<dim3(32, 24), 256, 0, stream>>>(xb, WtQKV, QKV, 4096, 3072, 1024);
  vtrans<<<dim3(64, 16, 2), 256, 0, stream>>>(QKV, Vtg);
  attn_kernel<<<dim3(16, 32), 256, 0, stream>>>(QKV, Vtg, Opart, Lpart);
  combine<<<2048, 256, 0, stream>>>(Opart, Lpart, Obuf);
  gemm_bt<0><<<dim3(32, 8), 256, 0, stream>>>(Obuf, WtO, out, 4096, 1024, 1024);
}

// Round 15
// 140.605 us; speedup vs baseline: 2.9429x; 2.9429x over previous
//
#include <hip/hip_runtime.h>

typedef unsigned short u16;
typedef unsigned int u32;
typedef __attribute__((ext_vector_type(8))) __bf16 bf16x8;
typedef __attribute__((ext_vector_type(2))) __bf16 bf16x2;
typedef __attribute__((ext_vector_type(4))) float f32x4;
typedef __attribute__((ext_vector_type(16))) float f32x16;
typedef __attribute__((ext_vector_type(4))) u32 u32x4;

__device__ inline u16 f2bf(float f) {
  unsigned u = __builtin_bit_cast(unsigned, f);
  u += 0x7FFFu + ((u >> 16) & 1u);
  return (u16)(u >> 16);
}

__device__ inline u32 packbf(float a, float b) {
  bf16x2 t;
  t[0] = (__bf16)a;
  t[1] = (__bf16)b;
  return __builtin_bit_cast(u32, t);
}

__device__ inline void async16(const void* g, void* l) {
  __builtin_amdgcn_global_load_lds((const __attribute__((address_space(1))) void*)g,
                                   (__attribute__((address_space(3))) void*)l, 16, 0, 0);
}

// ---------------- x fp32 -> bf16 ----------------
__global__ __launch_bounds__(256) void xconv(const float* __restrict__ x, u16* __restrict__ xb) {
  int i = blockIdx.x * 256 + threadIdx.x;
  float4 v = ((const float4*)x)[i];
  ushort4 r;
  r.x = f2bf(v.x); r.y = f2bf(v.y); r.z = f2bf(v.z); r.w = f2bf(v.w);
  ((ushort4*)xb)[i] = r;
}

// ---------------- all 4 weights: W (d,e) fp32 -> Wt (e,d) bf16, one launch ----------------
// z==0 (W_Q) folds 0.125*log2(e) so QK^T comes out in exp2 domain.
__global__ __launch_bounds__(256) void wtrans4(const float* __restrict__ W0,
                                               const float* __restrict__ W1,
                                               const float* __restrict__ W2,
                                               const float* __restrict__ W3,
                                               u16* __restrict__ WtQKV,
                                               u16* __restrict__ WtO) {
  __shared__ u16 tile[32][33];
  const int z = blockIdx.z;
  const float* W = (z == 0) ? W0 : (z == 1) ? W1 : (z == 2) ? W2 : W3;
  u16* Wt = (z < 3) ? (WtQKV + (size_t)z * 1024 * 1024) : WtO;
  const float s = (z == 0) ? 0.18033688011112042f : 1.0f;
  const int e0 = blockIdx.x * 32;
  const int d0 = blockIdx.y * 32;
  const int tx = threadIdx.x & 31;
  const int ty = threadIdx.x >> 5;
#pragma unroll
  for (int i = ty; i < 32; i += 8)
    tile[i][tx] = f2bf(W[(size_t)(d0 + i) * 1024 + e0 + tx] * s);
  __syncthreads();
#pragma unroll
  for (int i = ty; i < 32; i += 8)
    Wt[(size_t)(e0 + i) * 1024 + d0 + tx] = tile[tx][i];
}

// ---------------- V slice of QKV -> Vtg[b*1024+dg][s'] (transposed, k-permuted) ----------------
// sigma(k) swaps bits 2,3 of k (within each 32-block): Vtg position s' holds V[sigma(s')].
// This makes PV's A-fragment lane-uniform (pa = pk[4kc..4kc+3]) -- deletes all shfl swaps
// in attn. Exact transform (permutes the reduction index of P and V consistently).
__global__ __launch_bounds__(256) void vtrans(const u16* __restrict__ QKV, u16* __restrict__ Vtg) {
  __shared__ u16 t[32][66];
  const int tid = threadIdx.x;
  const int s0 = blockIdx.x * 32, dg0 = blockIdx.y * 64, b = blockIdx.z;
  {
    const int i = tid >> 3, c = (tid & 7) * 8;
    uint4 v = *(const uint4*)(QKV + (size_t)(b * 2048 + s0 + i) * 3072 + 2048 + dg0 + c);
    u16 tmp[8];
    *(uint4*)tmp = v;
#pragma unroll
    for (int e = 0; e < 8; ++e) t[i][c + e] = tmp[e];
  }
  __syncthreads();
  {
    const int r = tid >> 2, cg = (tid & 3) * 8;
    u16 tmp[8];
#pragma unroll
    for (int e = 0; e < 8; ++e) {
      const int x = cg + e;                                   // position within 32-block
      const int sx = (x & ~12) | ((x & 4) << 1) | ((x & 8) >> 1);  // sigma: swap bits 2,3
      tmp[e] = t[sx][r];
    }
    *(uint4*)(Vtg + (size_t)(b * 1024 + dg0 + r) * 2048 + s0 + cg) = *(uint4*)tmp;
  }
}

// ---------------- GEMM C[M,N] = A[M,K] * Bt[N,K]^T  (m97 structure) ----------------
template <int OUT_BF16>
__global__ __launch_bounds__(256) void gemm_bt(const u16* __restrict__ A,
                                               const u16* __restrict__ Bt,
                                               void* __restrict__ Cp,
                                               int M, int N, int K) {
  __shared__ __align__(16) u16 As[128 * 32];
  __shared__ __align__(16) u16 Bs[128 * 32];
  const int tid = threadIdx.x;
  const int lane = tid & 63;
  const int wave = tid >> 6;
  const int lr = lane & 15;
  const int lk = (lane >> 4) * 8;
  const int wm = (wave >> 1) * 64;
  const int wn = (wave & 1) * 64;
  const int bm = blockIdx.x * 128;
  const int bn = blockIdx.y * 128;
  const int srow = lane >> 2;
  const int scol = (lane & 3) * 8;

  f32x4 acc[4][4] = {};

  for (int k0 = 0; k0 < K; k0 += 32) {
#pragma unroll
    for (int r = 0; r < 2; ++r) {
      const int chunk = r * 4 + wave;
      const int row = chunk * 16 + srow;
      async16(A + (size_t)(bm + row) * K + k0 + scol, &As[chunk * 512 + lane * 8]);
      async16(Bt + (size_t)(bn + row) * K + k0 + scol, &Bs[chunk * 512 + lane * 8]);
    }
    __syncthreads();
    bf16x8 a[4], b[4];
#pragma unroll
    for (int i = 0; i < 4; ++i) {
      a[i] = *(const bf16x8*)&As[(wm + i * 16 + lr) * 32 + lk];
      b[i] = *(const bf16x8*)&Bs[(wn + i * 16 + lr) * 32 + lk];
    }
#pragma unroll
    for (int mi = 0; mi < 4; ++mi)
#pragma unroll
      for (int ni = 0; ni < 4; ++ni)
        acc[mi][ni] = __builtin_amdgcn_mfma_f32_16x16x32_bf16(a[mi], b[ni], acc[mi][ni], 0, 0, 0);
    __syncthreads();
  }

#pragma unroll
  for (int mi = 0; mi < 4; ++mi) {
#pragma unroll
    for (int ni = 0; ni < 4; ++ni) {
      const int col = bn + wn + ni * 16 + lr;
#pragma unroll
      for (int j = 0; j < 4; ++j) {
        const int row = bm + wm + mi * 16 + (lane >> 4) * 4 + j;
        if (OUT_BF16)
          ((u16*)Cp)[(size_t)row * N + col] = f2bf(acc[mi][ni][j]);
        else
          ((float*)Cp)[(size_t)row * N + col] = acc[mi][ni][j];
      }
    }
  }
}

// ---------------- Flash causal attention: 64 q/wave, shuffle-free PV via k-permutation ----------------
// R13 structure (proven: 65us) minus ALL ds_bpermutes: V is sigma-permuted in Vtg, so PV's
// A-fragment is just pk[4kc..4kc+3] -- lane-uniform, no cross-lane exchange, no lh select.
__global__ __launch_bounds__(256, 2) void attn_kernel(const u16* __restrict__ QKV,
                                                      const u16* __restrict__ Vtg,
                                                      u16* __restrict__ Opart,
                                                      float* __restrict__ Lpart) {
  constexpr int S = 2048, LD = 3072;
  constexpr float MFIX = 12.0f;
  __shared__ __align__(16) u16 Ks[2][64 * 64];
  __shared__ __align__(16) u16 Vs[2][64 * 64];

  const int g = 7 - (blockIdx.x >> 1);   // longest (g=7) first
  const int c = blockIdx.x & 1;
  const int bh = blockIdx.y;
  const int b = bh >> 4, h = bh & 15;
  const int tid = threadIdx.x, lane = tid & 63, w = tid >> 6;  // w = 0..3
  const int l31 = lane & 31, lh = lane >> 5;

  const int qbase = g * 256 + w * 64;    // wave owns 64 q rows (2 q-halves)
  const int ktlast = 4 * g + w;          // diagonal k-tile (same for both q-halves)
  const int ktbeg = c * (2 * g + 2);
  const int ktend = (c + 1) * (2 * g + 2);

  // Q fragments, both q-halves: lane holds Q[q=qbase+qh*32+l31][d = cc*16 + lh*8 + i]
  bf16x8 qf[2][4];
#pragma unroll
  for (int qh = 0; qh < 2; ++qh) {
    const u16* qrow = QKV + (size_t)(b * S + qbase + qh * 32 + l31) * LD + h * 64;
#pragma unroll
    for (int cc = 0; cc < 4; ++cc) qf[qh][cc] = *(const bf16x8*)(qrow + cc * 16 + lh * 8);
  }

  // staging: 512 16B chunks per 64x64 tile, TWO per thread, pre-swizzled source (rule #21)
  const int c0 = tid, c1 = tid + 256;
  const int r0 = c0 >> 3, x0 = ((c0 & 7) ^ (r0 & 7)) << 3;
  const int r1 = c1 >> 3, x1 = ((c1 & 7) ^ (r1 & 7)) << 3;
  const u16* Kbase = QKV + (size_t)b * S * LD + 1024 + h * 64;
  const u16* Vbase = Vtg + (size_t)bh * 64 * 2048;

#define STAGE(buf, kt_)                                                          \
  do {                                                                           \
    async16(Kbase + (size_t)((kt_)*64 + r0) * LD + x0, &Ks[buf][c0 * 8]);        \
    async16(Kbase + (size_t)((kt_)*64 + r1) * LD + x1, &Ks[buf][c1 * 8]);        \
    async16(Vbase + (size_t)r0 * 2048 + (kt_)*64 + x0, &Vs[buf][c0 * 8]);        \
    async16(Vbase + (size_t)r1 * 2048 + (kt_)*64 + x1, &Vs[buf][c1 * 8]);        \
  } while (0)

  // o[qhalf][dhalf]
  f32x16 o00 = {}, o01 = {}, o10 = {}, o11 = {};
  float l0 = 0.f, l1 = 0.f;

#define TREE16(dst, arr)                                                         \
  do {                                                                           \
    float v_[16];                                                                \
    _Pragma("unroll") for (int r_ = 0; r_ < 16; ++r_) v_[r_] = (arr)[r_];        \
    _Pragma("unroll") for (int s_ = 8; s_ >= 1; s_ >>= 1)                        \
      _Pragma("unroll") for (int r_ = 0; r_ < s_; ++r_) v_[r_] += v_[r_ + s_];   \
    dst += v_[0];                                                                \
  } while (0)

  // shuffle-free PV A-fragment: with sigma-permuted V, A(kc) = pk[4kc .. 4kc+3] verbatim
#define MAKE_PA(pa, pk, q4)                                                      \
  bf16x8 pa;                                                                     \
  {                                                                              \
    u32x4 wv_;                                                                   \
    wv_[0] = (pk)[(q4) + 0];                                                     \
    wv_[1] = (pk)[(q4) + 1];                                                     \
    wv_[2] = (pk)[(q4) + 2];                                                     \
    wv_[3] = (pk)[(q4) + 3];                                                     \
    pa = __builtin_bit_cast(bf16x8, wv_);                                        \
  }

  STAGE(0, ktbeg);

  int cur = 0;
  for (int kt = ktbeg; kt < ktend; ++kt) {
    if (kt + 1 < ktend) {
      STAGE(cur ^ 1, kt + 1);
      asm volatile("s_waitcnt vmcnt(4)" ::: "memory");   // wait ONLY tile kt's 4 loads
    } else {
      asm volatile("s_waitcnt vmcnt(0)" ::: "memory");
    }
    __builtin_amdgcn_s_barrier();
    __builtin_amdgcn_sched_barrier(0);

    const bool active = (kt <= ktlast);
    if (active) {
      const bool full = (kt < ktlast);   // not the diagonal tile
      const u16* ks = Ks[cur];
      const u16* vs = Vs[cur];

      // S^T quadrants t[khalf][qhalf] = K Q^T (exp2-scaled via W_Q folding)
      f32x16 t00 = {}, t10 = {}, t01 = {}, t11 = {};
      __builtin_amdgcn_s_setprio(1);
#pragma unroll
      for (int cc = 0; cc < 4; ++cc) {
        const int ci = 2 * cc + lh;
        const bf16x8 kf0 = *(const bf16x8*)&ks[l31 * 64 + ((ci ^ (l31 & 7)) << 3)];
        const bf16x8 kf1 = *(const bf16x8*)&ks[(32 + l31) * 64 + ((ci ^ (l31 & 7)) << 3)];
        t00 = __builtin_amdgcn_mfma_f32_32x32x16_bf16(kf0, qf[0][cc], t00, 0, 0, 0);
        t01 = __builtin_amdgcn_mfma_f32_32x32x16_bf16(kf0, qf[1][cc], t01, 0, 0, 0);
        if (full) t10 = __builtin_amdgcn_mfma_f32_32x32x16_bf16(kf1, qf[0][cc], t10, 0, 0, 0);
        t11 = __builtin_amdgcn_mfma_f32_32x32x16_bf16(kf1, qf[1][cc], t11, 0, 0, 0);
      }
      __builtin_amdgcn_s_setprio(0);

      // diagonal mask (original k-row space; sigma only permutes the PV reduction order)
      if (!full) {
#pragma unroll
        for (int r = 0; r < 16; ++r) {
          const int ko = (r & 3) + 8 * (r >> 2) + 4 * lh;
          if (ko > l31) { t00[r] = -3e38f; t11[r] = -3e38f; }
        }
      }

      u32 pk0[8], pk1[8];

      // ---- khalf0: exp, sum, pack, PV kc=0,1 ----
#pragma unroll
      for (int r = 0; r < 16; ++r) t00[r] = exp2f(t00[r] - MFIX);
#pragma unroll
      for (int r = 0; r < 16; ++r) t01[r] = exp2f(t01[r] - MFIX);
      TREE16(l0, t00);
      TREE16(l1, t01);
#pragma unroll
      for (int j = 0; j < 8; ++j) {
        pk0[j] = packbf(t00[2 * j], t00[2 * j + 1]);
        pk1[j] = packbf(t01[2 * j], t01[2 * j + 1]);
      }
      __builtin_amdgcn_s_setprio(1);
#pragma unroll
      for (int kc = 0; kc < 2; ++kc) {
        const int q4 = kc * 4;
        MAKE_PA(pa0, pk0, q4)
        MAKE_PA(pa1, pk1, q4)
        const int ci = 2 * kc + lh;
        const bf16x8 vd0 = *(const bf16x8*)&vs[l31 * 64 + ((ci ^ (l31 & 7)) << 3)];
        const bf16x8 vd1 = *(const bf16x8*)&vs[(32 + l31) * 64 + ((ci ^ (l31 & 7)) << 3)];
        o00 = __builtin_amdgcn_mfma_f32_32x32x16_bf16(pa0, vd0, o00, 0, 0, 0);
        o01 = __builtin_amdgcn_mfma_f32_32x32x16_bf16(pa0, vd1, o01, 0, 0, 0);
        o10 = __builtin_amdgcn_mfma_f32_32x32x16_bf16(pa1, vd0, o10, 0, 0, 0);
        o11 = __builtin_amdgcn_mfma_f32_32x32x16_bf16(pa1, vd1, o11, 0, 0, 0);
      }
      __builtin_amdgcn_s_setprio(0);

      // ---- khalf1: exp, sum, pack, PV kc=2,3 (qhalf0 skipped on diagonal) ----
      if (full) {
#pragma unroll
        for (int r = 0; r < 16; ++r) t10[r] = exp2f(t10[r] - MFIX);
        TREE16(l0, t10);
#pragma unroll
        for (int j = 0; j < 8; ++j) pk0[j] = packbf(t10[2 * j], t10[2 * j + 1]);
      }
#pragma unroll
      for (int r = 0; r < 16; ++r) t11[r] = exp2f(t11[r] - MFIX);
      TREE16(l1, t11);
#pragma unroll
      for (int j = 0; j < 8; ++j) pk1[j] = packbf(t11[2 * j], t11[2 * j + 1]);

      __builtin_amdgcn_s_setprio(1);
#pragma unroll
      for (int kc = 0; kc < 2; ++kc) {
        const int q4 = kc * 4;
        MAKE_PA(pa1, pk1, q4)
        const int ci = 2 * (kc + 2) + lh;
        const bf16x8 vd0 = *(const bf16x8*)&vs[l31 * 64 + ((ci ^ (l31 & 7)) << 3)];
        const bf16x8 vd1 = *(const bf16x8*)&vs[(32 + l31) * 64 + ((ci ^ (l31 & 7)) << 3)];
        if (full) {
          MAKE_PA(pa0, pk0, q4)
          o00 = __builtin_amdgcn_mfma_f32_32x32x16_bf16(pa0, vd0, o00, 0, 0, 0);
          o01 = __builtin_amdgcn_mfma_f32_32x32x16_bf16(pa0, vd1, o01, 0, 0, 0);
        }
        o10 = __builtin_amdgcn_mfma_f32_32x32x16_bf16(pa1, vd0, o10, 0, 0, 0);
        o11 = __builtin_amdgcn_mfma_f32_32x32x16_bf16(pa1, vd1, o11, 0, 0, 0);
      }
      __builtin_amdgcn_s_setprio(0);
    }

    asm volatile("s_waitcnt lgkmcnt(0)" ::: "memory");
    __builtin_amdgcn_s_barrier();
    cur ^= 1;
  }
#undef STAGE
#undef TREE16
#undef MAKE_PA

  // epilogue: store partial O (bf16, unnormalized) and partial l (f32)
  const float l0t = l0 + __shfl_xor(l0, 32);
  const float l1t = l1 + __shfl_xor(l1, 32);
  u16* Oc = Opart + (size_t)c * 4096 * 1024;
#pragma unroll
  for (int r = 0; r < 16; ++r) {
    const int qo = (r & 3) + 8 * (r >> 2) + 4 * lh;
    u16* p0 = Oc + (size_t)(b * S + qbase + qo) * 1024 + h * 64 + l31;
    u16* p1 = p0 + (size_t)32 * 1024;
    p0[0] = f2bf(o00[r]);
    p0[32] = f2bf(o01[r]);
    p1[0] = f2bf(o10[r]);
    p1[32] = f2bf(o11[r]);
  }
  if (lh == 0) {
    Lpart[(size_t)c * 4096 * 16 + (size_t)(b * S + qbase + l31) * 16 + h] = l0t;
    Lpart[(size_t)c * 4096 * 16 + (size_t)(b * S + qbase + 32 + l31) * 16 + h] = l1t;
  }
}

// ---------------- combine partials: Obuf = (O0 + O1) / (l0 + l1) ----------------
__global__ __launch_bounds__(256) void combine(const u16* __restrict__ Opart,
                                               const float* __restrict__ Lpart,
                                               u16* __restrict__ Obuf) {
  const int i = blockIdx.x * 256 + threadIdx.x;   // 524288 threads: 8 cols each
  const int row = i >> 7;
  const int cw = (i & 127) * 8;
  const int h = cw >> 6;
  const float l = Lpart[(size_t)row * 16 + h] + Lpart[(size_t)4096 * 16 + (size_t)row * 16 + h];
  const float inv = 1.0f / l;
  const bf16x8 a = *(const bf16x8*)(Opart + (size_t)row * 1024 + cw);
  const bf16x8 bq = *(const bf16x8*)(Opart + (size_t)4096 * 1024 + (size_t)row * 1024 + cw);
  u16 out[8];
#pragma unroll
  for (int j = 0; j < 8; ++j) out[j] = f2bf(((float)a[j] + (float)bq[j]) * inv);
  *(uint4*)(Obuf + (size_t)row * 1024 + cw) = *(uint4*)out;
}

extern "C" void kernel_launch(void* const* d_in, const int* in_sizes, int n_in,
                              void* d_out, int out_size, void* d_ws, size_t ws_size,
                              hipStream_t stream) {
  const float* x  = (const float*)d_in[0];
  const float* WQ = (const float*)d_in[1];
  const float* WK = (const float*)d_in[2];
  const float* WV = (const float*)d_in[3];
  const float* WO = (const float*)d_in[4];
  float* out = (float*)d_out;

  u16* xb    = (u16*)d_ws;                      // 4096*1024
  u16* WtQKV = xb + (size_t)4096 * 1024;        // 3072*1024
  u16* WtO   = WtQKV + (size_t)3072 * 1024;     // 1024*1024
  u16* QKV   = WtO + (size_t)1024 * 1024;       // 4096*3072
  u16* Obuf  = QKV + (size_t)4096 * 3072;       // 4096*1024
  u16* Vtg   = Obuf + (size_t)4096 * 1024;      // 2048*2048
  u16* Opart = Vtg + (size_t)2048 * 2048;       // 2 * 4096*1024 bf16
  float* Lpart = (float*)(Opart + (size_t)2 * 4096 * 1024);  // 2 * 4096*16 f32

  xconv<<<4096, 256, 0, stream>>>(x, xb);
  wtrans4<<<dim3(32, 32, 4), 256, 0, stream>>>(WQ, WK, WV, WO, WtQKV, WtO);

  gemm_bt<1><<<dim3(32, 24), 256, 0, stream>>>(xb, WtQKV, QKV, 4096, 3072, 1024);
  vtrans<<<dim3(64, 16, 2), 256, 0, stream>>>(QKV, Vtg);
  attn_kernel<<<dim3(16, 32), 256, 0, stream>>>(QKV, Vtg, Opart, Lpart);
  combine<<<2048, 256, 0, stream>>>(Opart, Lpart, Obuf);
  gemm_bt<0><<<dim3(32, 8), 256, 0, stream>>>(Obuf, WtO, out, 4096, 1024, 1024);
}

// Round 16
// 139.659 us; speedup vs baseline: 2.9628x; 1.0068x over previous
//
#include <hip/hip_runtime.h>

typedef unsigned short u16;
typedef unsigned int u32;
typedef __attribute__((ext_vector_type(8))) __bf16 bf16x8;
typedef __attribute__((ext_vector_type(2))) __bf16 bf16x2;
typedef __attribute__((ext_vector_type(4))) float f32x4;
typedef __attribute__((ext_vector_type(16))) float f32x16;
typedef __attribute__((ext_vector_type(4))) u32 u32x4;

__device__ inline u16 f2bf(float f) {
  unsigned u = __builtin_bit_cast(unsigned, f);
  u += 0x7FFFu + ((u >> 16) & 1u);
  return (u16)(u >> 16);
}

__device__ inline u32 packbf(float a, float b) {
  bf16x2 t;
  t[0] = (__bf16)a;
  t[1] = (__bf16)b;
  return __builtin_bit_cast(u32, t);
}

__device__ inline void async16(const void* g, void* l) {
  __builtin_amdgcn_global_load_lds((const __attribute__((address_space(1))) void*)g,
                                   (__attribute__((address_space(3))) void*)l, 16, 0, 0);
}

// ---------------- fused prep: x fp32->bf16 (z==4) + 4x weight transpose (z<4) ----------------
// z==0 (W_Q) folds 0.125*log2(e) so QK^T comes out in exp2 domain.
__global__ __launch_bounds__(256) void prep(const float* __restrict__ x, u16* __restrict__ xb,
                                            const float* __restrict__ W0,
                                            const float* __restrict__ W1,
                                            const float* __restrict__ W2,
                                            const float* __restrict__ W3,
                                            u16* __restrict__ WtQKV,
                                            u16* __restrict__ WtO) {
  const int z = blockIdx.z;
  if (z == 4) {
    const int base = (blockIdx.y * 32 + blockIdx.x) * 4 * 256 + threadIdx.x;
#pragma unroll
    for (int it = 0; it < 4; ++it) {
      const int i = base + it * 256;
      float4 v = ((const float4*)x)[i];
      ushort4 r;
      r.x = f2bf(v.x); r.y = f2bf(v.y); r.z = f2bf(v.z); r.w = f2bf(v.w);
      ((ushort4*)xb)[i] = r;
    }
    return;
  }
  __shared__ u16 tile[32][33];
  const float* W = (z == 0) ? W0 : (z == 1) ? W1 : (z == 2) ? W2 : W3;
  u16* Wt = (z < 3) ? (WtQKV + (size_t)z * 1024 * 1024) : WtO;
  const float s = (z == 0) ? 0.18033688011112042f : 1.0f;
  const int e0 = blockIdx.x * 32;
  const int d0 = blockIdx.y * 32;
  const int tx = threadIdx.x & 31;
  const int ty = threadIdx.x >> 5;
#pragma unroll
  for (int i = ty; i < 32; i += 8)
    tile[i][tx] = f2bf(W[(size_t)(d0 + i) * 1024 + e0 + tx] * s);
  __syncthreads();
#pragma unroll
  for (int i = ty; i < 32; i += 8)
    Wt[(size_t)(e0 + i) * 1024 + d0 + tx] = tile[tx][i];
}

// ---------------- V slice of QKV -> Vtg[b*1024+dg][s'] (transposed, k-permuted) ----------------
// sigma(k) swaps bits 2,3 of k (within each 32-block): makes PV's A-fragment lane-uniform.
__global__ __launch_bounds__(256) void vtrans(const u16* __restrict__ QKV, u16* __restrict__ Vtg) {
  __shared__ u16 t[32][66];
  const int tid = threadIdx.x;
  const int s0 = blockIdx.x * 32, dg0 = blockIdx.y * 64, b = blockIdx.z;
  {
    const int i = tid >> 3, c = (tid & 7) * 8;
    uint4 v = *(const uint4*)(QKV + (size_t)(b * 2048 + s0 + i) * 3072 + 2048 + dg0 + c);
    u16 tmp[8];
    *(uint4*)tmp = v;
#pragma unroll
    for (int e = 0; e < 8; ++e) t[i][c + e] = tmp[e];
  }
  __syncthreads();
  {
    const int r = tid >> 2, cg = (tid & 3) * 8;
    u16 tmp[8];
#pragma unroll
    for (int e = 0; e < 8; ++e) {
      const int x = cg + e;
      const int sx = (x & ~12) | ((x & 4) << 1) | ((x & 8) >> 1);  // sigma: swap bits 2,3
      tmp[e] = t[sx][r];
    }
    *(uint4*)(Vtg + (size_t)(b * 1024 + dg0 + r) * 2048 + s0 + cg) = *(uint4*)tmp;
  }
}

// ---------------- GEMM C[M,N] = A[M,K] * Bt[N,K]^T  (m97 structure) ----------------
template <int OUT_BF16>
__global__ __launch_bounds__(256) void gemm_bt(const u16* __restrict__ A,
                                               const u16* __restrict__ Bt,
                                               void* __restrict__ Cp,
                                               int M, int N, int K) {
  __shared__ __align__(16) u16 As[128 * 32];
  __shared__ __align__(16) u16 Bs[128 * 32];
  const int tid = threadIdx.x;
  const int lane = tid & 63;
  const int wave = tid >> 6;
  const int lr = lane & 15;
  const int lk = (lane >> 4) * 8;
  const int wm = (wave >> 1) * 64;
  const int wn = (wave & 1) * 64;
  const int bm = blockIdx.x * 128;
  const int bn = blockIdx.y * 128;
  const int srow = lane >> 2;
  const int scol = (lane & 3) * 8;

  f32x4 acc[4][4] = {};

  for (int k0 = 0; k0 < K; k0 += 32) {
#pragma unroll
    for (int r = 0; r < 2; ++r) {
      const int chunk = r * 4 + wave;
      const int row = chunk * 16 + srow;
      async16(A + (size_t)(bm + row) * K + k0 + scol, &As[chunk * 512 + lane * 8]);
      async16(Bt + (size_t)(bn + row) * K + k0 + scol, &Bs[chunk * 512 + lane * 8]);
    }
    __syncthreads();
    bf16x8 a[4], b[4];
#pragma unroll
    for (int i = 0; i < 4; ++i) {
      a[i] = *(const bf16x8*)&As[(wm + i * 16 + lr) * 32 + lk];
      b[i] = *(const bf16x8*)&Bs[(wn + i * 16 + lr) * 32 + lk];
    }
#pragma unroll
    for (int mi = 0; mi < 4; ++mi)
#pragma unroll
      for (int ni = 0; ni < 4; ++ni)
        acc[mi][ni] = __builtin_amdgcn_mfma_f32_16x16x32_bf16(a[mi], b[ni], acc[mi][ni], 0, 0, 0);
    __syncthreads();
  }

#pragma unroll
  for (int mi = 0; mi < 4; ++mi) {
#pragma unroll
    for (int ni = 0; ni < 4; ++ni) {
      const int col = bn + wn + ni * 16 + lr;
#pragma unroll
      for (int j = 0; j < 4; ++j) {
        const int row = bm + wm + mi * 16 + (lane >> 4) * 4 + j;
        if (OUT_BF16)
          ((u16*)Cp)[(size_t)row * N + col] = f2bf(acc[mi][ni][j]);
        else
          ((float*)Cp)[(size_t)row * N + col] = acc[mi][ni][j];
      }
    }
  }
}

// ---------------- Flash causal attention: KVBLK=128 (half the iterations/barriers) ----------------
// R15 structure with 128-row K/V tiles: same LDS ops + MFLOPs, half the barrier/vmcnt crossings.
// K tile [128][64] u16, V^T tile [64][128] u16, both XOR-swizzled (write/read pair, rule #21).
// sigma-permuted V keeps PV shuffle-free. 8 async16/thread/tile -> counted vmcnt(8).
__global__ __launch_bounds__(256, 2) void attn_kernel(const u16* __restrict__ QKV,
                                                      const u16* __restrict__ Vtg,
                                                      u16* __restrict__ Opart,
                                                      float* __restrict__ Lpart) {
  constexpr int S = 2048, LD = 3072;
  constexpr float MFIX = 12.0f;
  __shared__ __align__(16) u16 Ks[2][128 * 64];
  __shared__ __align__(16) u16 Vs[2][64 * 128];

  const int g = 7 - (blockIdx.x >> 1);   // longest (g=7) first
  const int c = blockIdx.x & 1;
  const int bh = blockIdx.y;
  const int b = bh >> 4, h = bh & 15;
  const int tid = threadIdx.x, lane = tid & 63, w = tid >> 6;  // w = 0..3
  const int l31 = lane & 31, lh = lane >> 5;

  const int qbase = g * 256 + w * 64;    // wave owns 64 q rows (2 q-halves)
  const int ktlast = 2 * g + (w >> 1);   // diagonal 128-tile for this wave
  const int qblk = (w & 1) * 2;          // q-half 0's 32-block index within the 128-tile
  const int ktbeg = c * (g + 1);
  const int ktend = (c + 1) * (g + 1);

  // Q fragments, both q-halves: lane holds Q[q=qbase+qh*32+l31][d = cc*16 + lh*8 + i]
  bf16x8 qf[2][4];
#pragma unroll
  for (int qh = 0; qh < 2; ++qh) {
    const u16* qrow = QKV + (size_t)(b * S + qbase + qh * 32 + l31) * LD + h * 64;
#pragma unroll
    for (int cc = 0; cc < 4; ++cc) qf[qh][cc] = *(const bf16x8*)(qrow + cc * 16 + lh * 8);
  }

  const u16* Kbase = QKV + (size_t)b * S * LD + 1024 + h * 64;
  const u16* Vbase = Vtg + (size_t)bh * 64 * 2048;

  // staging: K tile 1024 chunks [r=chunk>>3][c=chunk&7], V tile 1024 chunks [d=chunk>>4][c=chunk&15]
  // pre-swizzled global source (rule #21): K col (c^(r&7))<<3, V col (c^(d&7))<<3
#define STAGE(buf, kt_)                                                                 \
  do {                                                                                  \
    _Pragma("unroll") for (int i_ = 0; i_ < 4; ++i_) {                                  \
      const int ch = tid + 256 * i_;                                                    \
      const int kr = ch >> 3, kc = ch & 7;                                              \
      async16(Kbase + (size_t)((kt_)*128 + kr) * LD + ((kc ^ (kr & 7)) << 3),           \
              &Ks[buf][ch * 8]);                                                        \
    }                                                                                   \
    _Pragma("unroll") for (int i_ = 0; i_ < 4; ++i_) {                                  \
      const int ch = tid + 256 * i_;                                                    \
      const int vd = ch >> 4, vc = ch & 15;                                             \
      async16(Vbase + (size_t)vd * 2048 + (kt_)*128 + ((vc ^ (vd & 7)) << 3),           \
              &Vs[buf][ch * 8]);                                                        \
    }                                                                                   \
  } while (0)

  // o[qhalf][dhalf]
  f32x16 o00 = {}, o01 = {}, o10 = {}, o11 = {};
  float l0 = 0.f, l1 = 0.f;

#define TREE16(dst, arr)                                                         \
  do {                                                                           \
    float v_[16];                                                                \
    _Pragma("unroll") for (int r_ = 0; r_ < 16; ++r_) v_[r_] = (arr)[r_];        \
    _Pragma("unroll") for (int s_ = 8; s_ >= 1; s_ >>= 1)                        \
      _Pragma("unroll") for (int r_ = 0; r_ < s_; ++r_) v_[r_] += v_[r_ + s_];   \
    dst += v_[0];                                                                \
  } while (0)

  // shuffle-free PV A-fragment (sigma-permuted V): A(kc) = pk[4kc .. 4kc+3] verbatim
#define MAKE_PA(pa, pk, q4)                                                      \
  bf16x8 pa;                                                                     \
  {                                                                              \
    u32x4 wv_;                                                                   \
    wv_[0] = (pk)[(q4) + 0];                                                     \
    wv_[1] = (pk)[(q4) + 1];                                                     \
    wv_[2] = (pk)[(q4) + 2];                                                     \
    wv_[3] = (pk)[(q4) + 3];                                                     \
    pa = __builtin_bit_cast(bf16x8, wv_);                                        \
  }

  STAGE(0, ktbeg);

  int cur = 0;
  for (int kt = ktbeg; kt < ktend; ++kt) {
    if (kt + 1 < ktend) {
      STAGE(cur ^ 1, kt + 1);
      asm volatile("s_waitcnt vmcnt(8)" ::: "memory");   // wait ONLY tile kt's 8 loads
    } else {
      asm volatile("s_waitcnt vmcnt(0)" ::: "memory");
    }
    __builtin_amdgcn_s_barrier();
    __builtin_amdgcn_sched_barrier(0);

    if (kt <= ktlast) {
      const bool dtile = (kt == ktlast);
      const u16* ks = Ks[cur];
      const u16* vs = Vs[cur];

      // 4 k-groups of 32 within the 128-tile
#pragma unroll
      for (int kq = 0; kq < 4; ++kq) {
        // per (kq, qh) status: full if kq < qblk+qh (or non-diag tile); diag if ==; masked if >
        const bool en0 = !dtile || (kq <= qblk);
        const bool en1 = !dtile || (kq <= qblk + 1);
        const bool dg0 = dtile && (kq == qblk);
        const bool dg1 = dtile && (kq == qblk + 1);
        if (!en1) break;   // kq increasing: nothing left this tile

        // S^T = K Q^T for this k-group (exp2-scaled via W_Q folding)
        f32x16 t0 = {}, t1 = {};
        __builtin_amdgcn_s_setprio(1);
#pragma unroll
        for (int cc = 0; cc < 4; ++cc) {
          const int ci = 2 * cc + lh;
          const bf16x8 kf = *(const bf16x8*)&ks[(kq * 32 + l31) * 64 + ((ci ^ (l31 & 7)) << 3)];
          if (en0) t0 = __builtin_amdgcn_mfma_f32_32x32x16_bf16(kf, qf[0][cc], t0, 0, 0, 0);
          t1 = __builtin_amdgcn_mfma_f32_32x32x16_bf16(kf, qf[1][cc], t1, 0, 0, 0);
        }
        __builtin_amdgcn_s_setprio(0);

        // diagonal mask within the 32x32 block (original k-row space)
        if (dg0 || dg1) {
#pragma unroll
          for (int r = 0; r < 16; ++r) {
            const int ko = (r & 3) + 8 * (r >> 2) + 4 * lh;
            if (dg0 && ko > l31) t0[r] = -3e38f;
            if (dg1 && ko > l31) t1[r] = -3e38f;
          }
        }

        u32 pk0[8], pk1[8];
        if (en0) {
#pragma unroll
          for (int r = 0; r < 16; ++r) t0[r] = exp2f(t0[r] - MFIX);
          TREE16(l0, t0);
#pragma unroll
          for (int j = 0; j < 8; ++j) pk0[j] = packbf(t0[2 * j], t0[2 * j + 1]);
        }
#pragma unroll
        for (int r = 0; r < 16; ++r) t1[r] = exp2f(t1[r] - MFIX);
        TREE16(l1, t1);
#pragma unroll
        for (int j = 0; j < 8; ++j) pk1[j] = packbf(t1[2 * j], t1[2 * j + 1]);

        // O += P V for this k-group
        __builtin_amdgcn_s_setprio(1);
#pragma unroll
        for (int kc = 0; kc < 2; ++kc) {
          const int ci = kq * 4 + 2 * kc + lh;
          const bf16x8 vd0 = *(const bf16x8*)&vs[l31 * 128 + ((ci ^ (l31 & 7)) << 3)];
          const bf16x8 vd1 = *(const bf16x8*)&vs[(32 + l31) * 128 + ((ci ^ (l31 & 7)) << 3)];
          MAKE_PA(pa1, pk1, kc * 4)
          if (en0) {
            MAKE_PA(pa0, pk0, kc * 4)
            o00 = __builtin_amdgcn_mfma_f32_32x32x16_bf16(pa0, vd0, o00, 0, 0, 0);
            o01 = __builtin_amdgcn_mfma_f32_32x32x16_bf16(pa0, vd1, o01, 0, 0, 0);
          }
          o10 = __builtin_amdgcn_mfma_f32_32x32x16_bf16(pa1, vd0, o10, 0, 0, 0);
          o11 = __builtin_amdgcn_mfma_f32_32x32x16_bf16(pa1, vd1, o11, 0, 0, 0);
        }
        __builtin_amdgcn_s_setprio(0);
      }
    }

    asm volatile("s_waitcnt lgkmcnt(0)" ::: "memory");
    __builtin_amdgcn_s_barrier();
    cur ^= 1;
  }
#undef STAGE
#undef TREE16
#undef MAKE_PA

  // epilogue: store partial O (bf16, unnormalized) and partial l (f32)
  const float l0t = l0 + __shfl_xor(l0, 32);
  const float l1t = l1 + __shfl_xor(l1, 32);
  u16* Oc = Opart + (size_t)c * 4096 * 1024;
#pragma unroll
  for (int r = 0; r < 16; ++r) {
    const int qo = (r & 3) + 8 * (r >> 2) + 4 * lh;
    u16* p0 = Oc + (size_t)(b * S + qbase + qo) * 1024 + h * 64 + l31;
    u16* p1 = p0 + (size_t)32 * 1024;
    p0[0] = f2bf(o00[r]);
    p0[32] = f2bf(o01[r]);
    p1[0] = f2bf(o10[r]);
    p1[32] = f2bf(o11[r]);
  }
  if (lh == 0) {
    Lpart[(size_t)c * 4096 * 16 + (size_t)(b * S + qbase + l31) * 16 + h] = l0t;
    Lpart[(size_t)c * 4096 * 16 + (size_t)(b * S + qbase + 32 + l31) * 16 + h] = l1t;
  }
}

// ---------------- combine partials: Obuf = (O0 + O1) / (l0 + l1) ----------------
__global__ __launch_bounds__(256) void combine(const u16* __restrict__ Opart,
                                               const float* __restrict__ Lpart,
                                               u16* __restrict__ Obuf) {
  const int i = blockIdx.x * 256 + threadIdx.x;
  const int row = i >> 7;
  const int cw = (i & 127) * 8;
  const int h = cw >> 6;
  const float l = Lpart[(size_t)row * 16 + h] + Lpart[(size_t)4096 * 16 + (size_t)row * 16 + h];
  const float inv = 1.0f / l;
  const bf16x8 a = *(const bf16x8*)(Opart + (size_t)row * 1024 + cw);
  const bf16x8 bq = *(const bf16x8*)(Opart + (size_t)4096 * 1024 + (size_t)row * 1024 + cw);
  u16 out[8];
#pragma unroll
  for (int j = 0; j < 8; ++j) out[j] = f2bf(((float)a[j] + (float)bq[j]) * inv);
  *(uint4*)(Obuf + (size_t)row * 1024 + cw) = *(uint4*)out;
}

extern "C" void kernel_launch(void* const* d_in, const int* in_sizes, int n_in,
                              void* d_out, int out_size, void* d_ws, size_t ws_size,
                              hipStream_t stream) {
  const float* x  = (const float*)d_in[0];
  const float* WQ = (const float*)d_in[1];
  const float* WK = (const float*)d_in[2];
  const float* WV = (const float*)d_in[3];
  const float* WO = (const float*)d_in[4];
  float* out = (float*)d_out;

  u16* xb    = (u16*)d_ws;                      // 4096*1024
  u16* WtQKV = xb + (size_t)4096 * 1024;        // 3072*1024
  u16* WtO   = WtQKV + (size_t)3072 * 1024;     // 1024*1024
  u16* QKV   = WtO + (size_t)1024 * 1024;       // 4096*3072
  u16* Obuf  = QKV + (size_t)4096 * 3072;       // 4096*1024
  u16* Vtg   = Obuf + (size_t)4096 * 1024;      // 2048*2048
  u16* Opart = Vtg + (size_t)2048 * 2048;       // 2 * 4096*1024 bf16
  float* Lpart = (float*)(Opart + (size_t)2 * 4096 * 1024);  // 2 * 4096*16 f32

  prep<<<dim3(32, 32, 5), 256, 0, stream>>>(x, xb, WQ, WK, WV, WO, WtQKV, WtO);

  gemm_bt<1><<<dim3(32, 24), 256, 0, stream>>>(xb, WtQKV, QKV, 4096, 3072, 1024);
  vtrans<<<dim3(64, 16, 2), 256, 0, stream>>>(QKV, Vtg);
  attn_kernel<<<dim3(16, 32), 256, 0, stream>>>(QKV, Vtg, Opart, Lpart);
  combine<<<2048, 256, 0, stream>>>(Opart, Lpart, Obuf);
  gemm_bt<0><<<dim3(32, 8), 256, 0, stream>>>(Obuf, WtO, out, 4096, 1024, 1024);
}

// Round 17
// 138.224 us; speedup vs baseline: 2.9936x; 1.0104x over previous
//
#include <hip/hip_runtime.h>

typedef unsigned short u16;
typedef unsigned int u32;
typedef __attribute__((ext_vector_type(8))) __bf16 bf16x8;
typedef __attribute__((ext_vector_type(2))) __bf16 bf16x2;
typedef __attribute__((ext_vector_type(4))) float f32x4;
typedef __attribute__((ext_vector_type(16))) float f32x16;
typedef __attribute__((ext_vector_type(4))) u32 u32x4;

__device__ inline u16 f2bf(float f) {
  unsigned u = __builtin_bit_cast(unsigned, f);
  u += 0x7FFFu + ((u >> 16) & 1u);
  return (u16)(u >> 16);
}

__device__ inline u32 packbf(float a, float b) {
  bf16x2 t;
  t[0] = (__bf16)a;
  t[1] = (__bf16)b;
  return __builtin_bit_cast(u32, t);
}

__device__ inline void async16(const void* g, void* l) {
  __builtin_amdgcn_global_load_lds((const __attribute__((address_space(1))) void*)g,
                                   (__attribute__((address_space(3))) void*)l, 16, 0, 0);
}

// ---------------- fused prep: x fp32->bf16 (z==4) + 4x weight transpose (z<4) ----------------
// z==0 (W_Q) folds 0.125*log2(e) so QK^T comes out in exp2 domain.
__global__ __launch_bounds__(256) void prep(const float* __restrict__ x, u16* __restrict__ xb,
                                            const float* __restrict__ W0,
                                            const float* __restrict__ W1,
                                            const float* __restrict__ W2,
                                            const float* __restrict__ W3,
                                            u16* __restrict__ WtQKV,
                                            u16* __restrict__ WtO) {
  const int z = blockIdx.z;
  if (z == 4) {
    const int base = (blockIdx.y * 32 + blockIdx.x) * 4 * 256 + threadIdx.x;
#pragma unroll
    for (int it = 0; it < 4; ++it) {
      const int i = base + it * 256;
      float4 v = ((const float4*)x)[i];
      ushort4 r;
      r.x = f2bf(v.x); r.y = f2bf(v.y); r.z = f2bf(v.z); r.w = f2bf(v.w);
      ((ushort4*)xb)[i] = r;
    }
    return;
  }
  __shared__ u16 tile[32][33];
  const float* W = (z == 0) ? W0 : (z == 1) ? W1 : (z == 2) ? W2 : W3;
  u16* Wt = (z < 3) ? (WtQKV + (size_t)z * 1024 * 1024) : WtO;
  const float s = (z == 0) ? 0.18033688011112042f : 1.0f;
  const int e0 = blockIdx.x * 32;
  const int d0 = blockIdx.y * 32;
  const int tx = threadIdx.x & 31;
  const int ty = threadIdx.x >> 5;
#pragma unroll
  for (int i = ty; i < 32; i += 8)
    tile[i][tx] = f2bf(W[(size_t)(d0 + i) * 1024 + e0 + tx] * s);
  __syncthreads();
#pragma unroll
  for (int i = ty; i < 32; i += 8)
    Wt[(size_t)(e0 + i) * 1024 + d0 + tx] = tile[tx][i];
}

// ---------------- GEMM C[M,N] = A[M,K] * Bt[N,K]^T  (m97 structure + XCD swizzle) ----------------
// FUSE_V: for output cols >= 2048 (the V slice of QKV) also write sigma-permuted transposed
// copy into Vtg[b*1024+dg][sigma(s)] -- replaces the standalone vtrans kernel (bit-identical:
// sigma touches only bits 2,3 of s; the j=0..3 run stays a contiguous aligned ushort4).
template <int OUT_BF16, int FUSE_V>
__global__ __launch_bounds__(256) void gemm_bt(const u16* __restrict__ A,
                                               const u16* __restrict__ Bt,
                                               void* __restrict__ Cp,
                                               u16* __restrict__ Vtg,
                                               int M, int N, int K) {
  __shared__ __align__(16) u16 As[128 * 32];
  __shared__ __align__(16) u16 Bs[128 * 32];
  const int tid = threadIdx.x;
  const int lane = tid & 63;
  const int wave = tid >> 6;
  const int lr = lane & 15;
  const int lk = (lane >> 4) * 8;
  const int wm = (wave >> 1) * 64;
  const int wn = (wave & 1) * 64;

  // chunked XCD swizzle (bijective: nwg % 8 == 0 for both call sites)
  const int flat = blockIdx.y * gridDim.x + blockIdx.x;
  const int chunk = (gridDim.x * gridDim.y) >> 3;
  const int nf = (flat & 7) * chunk + (flat >> 3);
  const int bm = (nf % gridDim.x) * 128;
  const int bn = (nf / gridDim.x) * 128;

  const int srow = lane >> 2;
  const int scol = (lane & 3) * 8;

  f32x4 acc[4][4] = {};

  for (int k0 = 0; k0 < K; k0 += 32) {
#pragma unroll
    for (int r = 0; r < 2; ++r) {
      const int chnk = r * 4 + wave;
      const int row = chnk * 16 + srow;
      async16(A + (size_t)(bm + row) * K + k0 + scol, &As[chnk * 512 + lane * 8]);
      async16(Bt + (size_t)(bn + row) * K + k0 + scol, &Bs[chnk * 512 + lane * 8]);
    }
    __syncthreads();
    bf16x8 a[4], b[4];
#pragma unroll
    for (int i = 0; i < 4; ++i) {
      a[i] = *(const bf16x8*)&As[(wm + i * 16 + lr) * 32 + lk];
      b[i] = *(const bf16x8*)&Bs[(wn + i * 16 + lr) * 32 + lk];
    }
#pragma unroll
    for (int mi = 0; mi < 4; ++mi)
#pragma unroll
      for (int ni = 0; ni < 4; ++ni)
        acc[mi][ni] = __builtin_amdgcn_mfma_f32_16x16x32_bf16(a[mi], b[ni], acc[mi][ni], 0, 0, 0);
    __syncthreads();
  }

#pragma unroll
  for (int mi = 0; mi < 4; ++mi) {
    const int row = bm + wm + mi * 16 + (lane >> 4) * 4;   // j=0 row; j spans row..row+3
#pragma unroll
    for (int ni = 0; ni < 4; ++ni) {
      const int col = bn + wn + ni * 16 + lr;
#pragma unroll
      for (int j = 0; j < 4; ++j) {
        if (OUT_BF16)
          ((u16*)Cp)[(size_t)(row + j) * N + col] = f2bf(acc[mi][ni][j]);
        else
          ((float*)Cp)[(size_t)(row + j) * N + col] = acc[mi][ni][j];
      }
      if (FUSE_V && col >= 2048) {
        const int bloc = row >> 11;
        const int s = row & 2047;
        const int sp = (s & ~12) | ((s & 4) << 1) | ((s & 8) >> 1);  // sigma: swap bits 2,3
        ushort4 v4;
        v4.x = f2bf(acc[mi][ni][0]);
        v4.y = f2bf(acc[mi][ni][1]);
        v4.z = f2bf(acc[mi][ni][2]);
        v4.w = f2bf(acc[mi][ni][3]);
        *(ushort4*)(Vtg + (size_t)(bloc * 1024 + (col - 2048)) * 2048 + sp) = v4;
      }
    }
  }
}

// ---------------- Flash causal attention: R15 body (KVBLK=64, proven 58.3us) + XCD swizzle ----------------
// 64 q/wave, shuffle-free PV via sigma-permuted V, KV-split=2, fixed-m softmax, counted vmcnt(4).
// Chunked XCD swizzle: each XCD owns 4 consecutive bh -> 2MB KV working set fits its 4MB L2.
__global__ __launch_bounds__(256, 2) void attn_kernel(const u16* __restrict__ QKV,
                                                      const u16* __restrict__ Vtg,
                                                      u16* __restrict__ Opart,
                                                      float* __restrict__ Lpart) {
  constexpr int S = 2048, LD = 3072;
  constexpr float MFIX = 12.0f;
  __shared__ __align__(16) u16 Ks[2][64 * 64];
  __shared__ __align__(16) u16 Vs[2][64 * 64];

  // chunked XCD swizzle over 512 blocks (512 % 8 == 0, bijective)
  const int flat = blockIdx.y * 16 + blockIdx.x;
  const int nf = (flat & 7) * 64 + (flat >> 3);
  const int xi = nf & 15;
  const int bh = nf >> 4;

  const int g = 7 - (xi >> 1);   // longest (g=7) first within each XCD's sequence
  const int c = xi & 1;
  const int b = bh >> 4, h = bh & 15;
  const int tid = threadIdx.x, lane = tid & 63, w = tid >> 6;  // w = 0..3
  const int l31 = lane & 31, lh = lane >> 5;

  const int qbase = g * 256 + w * 64;    // wave owns 64 q rows (2 q-halves)
  const int ktlast = 4 * g + w;          // diagonal k-tile (same for both q-halves)
  const int ktbeg = c * (2 * g + 2);
  const int ktend = (c + 1) * (2 * g + 2);

  // Q fragments, both q-halves: lane holds Q[q=qbase+qh*32+l31][d = cc*16 + lh*8 + i]
  bf16x8 qf[2][4];
#pragma unroll
  for (int qh = 0; qh < 2; ++qh) {
    const u16* qrow = QKV + (size_t)(b * S + qbase + qh * 32 + l31) * LD + h * 64;
#pragma unroll
    for (int cc = 0; cc < 4; ++cc) qf[qh][cc] = *(const bf16x8*)(qrow + cc * 16 + lh * 8);
  }

  // staging: 512 16B chunks per 64x64 tile, TWO per thread, pre-swizzled source (rule #21)
  const int c0 = tid, c1 = tid + 256;
  const int r0 = c0 >> 3, x0 = ((c0 & 7) ^ (r0 & 7)) << 3;
  const int r1 = c1 >> 3, x1 = ((c1 & 7) ^ (r1 & 7)) << 3;
  const u16* Kbase = QKV + (size_t)b * S * LD + 1024 + h * 64;
  const u16* Vbase = Vtg + (size_t)bh * 64 * 2048;

#define STAGE(buf, kt_)                                                          \
  do {                                                                           \
    async16(Kbase + (size_t)((kt_)*64 + r0) * LD + x0, &Ks[buf][c0 * 8]);        \
    async16(Kbase + (size_t)((kt_)*64 + r1) * LD + x1, &Ks[buf][c1 * 8]);        \
    async16(Vbase + (size_t)r0 * 2048 + (kt_)*64 + x0, &Vs[buf][c0 * 8]);        \
    async16(Vbase + (size_t)r1 * 2048 + (kt_)*64 + x1, &Vs[buf][c1 * 8]);        \
  } while (0)

  // o[qhalf][dhalf]
  f32x16 o00 = {}, o01 = {}, o10 = {}, o11 = {};
  float l0 = 0.f, l1 = 0.f;

#define TREE16(dst, arr)                                                         \
  do {                                                                           \
    float v_[16];                                                                \
    _Pragma("unroll") for (int r_ = 0; r_ < 16; ++r_) v_[r_] = (arr)[r_];        \
    _Pragma("unroll") for (int s_ = 8; s_ >= 1; s_ >>= 1)                        \
      _Pragma("unroll") for (int r_ = 0; r_ < s_; ++r_) v_[r_] += v_[r_ + s_];   \
    dst += v_[0];                                                                \
  } while (0)

  // shuffle-free PV A-fragment (sigma-permuted V): A(kc) = pk[4kc .. 4kc+3] verbatim
#define MAKE_PA(pa, pk, q4)                                                      \
  bf16x8 pa;                                                                     \
  {                                                                              \
    u32x4 wv_;                                                                   \
    wv_[0] = (pk)[(q4) + 0];                                                     \
    wv_[1] = (pk)[(q4) + 1];                                                     \
    wv_[2] = (pk)[(q4) + 2];                                                     \
    wv_[3] = (pk)[(q4) + 3];                                                     \
    pa = __builtin_bit_cast(bf16x8, wv_);                                        \
  }

  STAGE(0, ktbeg);

  int cur = 0;
  for (int kt = ktbeg; kt < ktend; ++kt) {
    if (kt + 1 < ktend) {
      STAGE(cur ^ 1, kt + 1);
      asm volatile("s_waitcnt vmcnt(4)" ::: "memory");   // wait ONLY tile kt's 4 loads
    } else {
      asm volatile("s_waitcnt vmcnt(0)" ::: "memory");
    }
    __builtin_amdgcn_s_barrier();
    __builtin_amdgcn_sched_barrier(0);

    const bool active = (kt <= ktlast);
    if (active) {
      const bool full = (kt < ktlast);   // not the diagonal tile
      const u16* ks = Ks[cur];
      const u16* vs = Vs[cur];

      // S^T quadrants t[khalf][qhalf] = K Q^T (exp2-scaled via W_Q folding)
      f32x16 t00 = {}, t10 = {}, t01 = {}, t11 = {};
      __builtin_amdgcn_s_setprio(1);
#pragma unroll
      for (int cc = 0; cc < 4; ++cc) {
        const int ci = 2 * cc + lh;
        const bf16x8 kf0 = *(const bf16x8*)&ks[l31 * 64 + ((ci ^ (l31 & 7)) << 3)];
        const bf16x8 kf1 = *(const bf16x8*)&ks[(32 + l31) * 64 + ((ci ^ (l31 & 7)) << 3)];
        t00 = __builtin_amdgcn_mfma_f32_32x32x16_bf16(kf0, qf[0][cc], t00, 0, 0, 0);
        t01 = __builtin_amdgcn_mfma_f32_32x32x16_bf16(kf0, qf[1][cc], t01, 0, 0, 0);
        if (full) t10 = __builtin_amdgcn_mfma_f32_32x32x16_bf16(kf1, qf[0][cc], t10, 0, 0, 0);
        t11 = __builtin_amdgcn_mfma_f32_32x32x16_bf16(kf1, qf[1][cc], t11, 0, 0, 0);
      }
      __builtin_amdgcn_s_setprio(0);

      // diagonal mask (original k-row space; sigma only permutes the PV reduction order)
      if (!full) {
#pragma unroll
        for (int r = 0; r < 16; ++r) {
          const int ko = (r & 3) + 8 * (r >> 2) + 4 * lh;
          if (ko > l31) { t00[r] = -3e38f; t11[r] = -3e38f; }
        }
      }

      u32 pk0[8], pk1[8];

      // ---- khalf0: exp, sum, pack, PV kc=0,1 ----
#pragma unroll
      for (int r = 0; r < 16; ++r) t00[r] = exp2f(t00[r] - MFIX);
#pragma unroll
      for (int r = 0; r < 16; ++r) t01[r] = exp2f(t01[r] - MFIX);
      TREE16(l0, t00);
      TREE16(l1, t01);
#pragma unroll
      for (int j = 0; j < 8; ++j) {
        pk0[j] = packbf(t00[2 * j], t00[2 * j + 1]);
        pk1[j] = packbf(t01[2 * j], t01[2 * j + 1]);
      }
      __builtin_amdgcn_s_setprio(1);
#pragma unroll
      for (int kc = 0; kc < 2; ++kc) {
        const int q4 = kc * 4;
        MAKE_PA(pa0, pk0, q4)
        MAKE_PA(pa1, pk1, q4)
        const int ci = 2 * kc + lh;
        const bf16x8 vd0 = *(const bf16x8*)&vs[l31 * 64 + ((ci ^ (l31 & 7)) << 3)];
        const bf16x8 vd1 = *(const bf16x8*)&vs[(32 + l31) * 64 + ((ci ^ (l31 & 7)) << 3)];
        o00 = __builtin_amdgcn_mfma_f32_32x32x16_bf16(pa0, vd0, o00, 0, 0, 0);
        o01 = __builtin_amdgcn_mfma_f32_32x32x16_bf16(pa0, vd1, o01, 0, 0, 0);
        o10 = __builtin_amdgcn_mfma_f32_32x32x16_bf16(pa1, vd0, o10, 0, 0, 0);
        o11 = __builtin_amdgcn_mfma_f32_32x32x16_bf16(pa1, vd1, o11, 0, 0, 0);
      }
      __builtin_amdgcn_s_setprio(0);

      // ---- khalf1: exp, sum, pack, PV kc=2,3 (qhalf0 skipped on diagonal) ----
      if (full) {
#pragma unroll
        for (int r = 0; r < 16; ++r) t10[r] = exp2f(t10[r] - MFIX);
        TREE16(l0, t10);
#pragma unroll
        for (int j = 0; j < 8; ++j) pk0[j] = packbf(t10[2 * j], t10[2 * j + 1]);
      }
#pragma unroll
      for (int r = 0; r < 16; ++r) t11[r] = exp2f(t11[r] - MFIX);
      TREE16(l1, t11);
#pragma unroll
      for (int j = 0; j < 8; ++j) pk1[j] = packbf(t11[2 * j], t11[2 * j + 1]);

      __builtin_amdgcn_s_setprio(1);
#pragma unroll
      for (int kc = 0; kc < 2; ++kc) {
        const int q4 = kc * 4;
        MAKE_PA(pa1, pk1, q4)
        const int ci = 2 * (kc + 2) + lh;
        const bf16x8 vd0 = *(const bf16x8*)&vs[l31 * 64 + ((ci ^ (l31 & 7)) << 3)];
        const bf16x8 vd1 = *(const bf16x8*)&vs[(32 + l31) * 64 + ((ci ^ (l31 & 7)) << 3)];
        if (full) {
          MAKE_PA(pa0, pk0, q4)
          o00 = __builtin_amdgcn_mfma_f32_32x32x16_bf16(pa0, vd0, o00, 0, 0, 0);
          o01 = __builtin_amdgcn_mfma_f32_32x32x16_bf16(pa0, vd1, o01, 0, 0, 0);
        }
        o10 = __builtin_amdgcn_mfma_f32_32x32x16_bf16(pa1, vd0, o10, 0, 0, 0);
        o11 = __builtin_amdgcn_mfma_f32_32x32x16_bf16(pa1, vd1, o11, 0, 0, 0);
      }
      __builtin_amdgcn_s_setprio(0);
    }

    asm volatile("s_waitcnt lgkmcnt(0)" ::: "memory");
    __builtin_amdgcn_s_barrier();
    cur ^= 1;
  }
#undef STAGE
#undef TREE16
#undef MAKE_PA

  // epilogue: store partial O (bf16, unnormalized) and partial l (f32)
  const float l0t = l0 + __shfl_xor(l0, 32);
  const float l1t = l1 + __shfl_xor(l1, 32);
  u16* Oc = Opart + (size_t)c * 4096 * 1024;
#pragma unroll
  for (int r = 0; r < 16; ++r) {
    const int qo = (r & 3) + 8 * (r >> 2) + 4 * lh;
    u16* p0 = Oc + (size_t)(b * S + qbase + qo) * 1024 + h * 64 + l31;
    u16* p1 = p0 + (size_t)32 * 1024;
    p0[0] = f2bf(o00[r]);
    p0[32] = f2bf(o01[r]);
    p1[0] = f2bf(o10[r]);
    p1[32] = f2bf(o11[r]);
  }
  if (lh == 0) {
    Lpart[(size_t)c * 4096 * 16 + (size_t)(b * S + qbase + l31) * 16 + h] = l0t;
    Lpart[(size_t)c * 4096 * 16 + (size_t)(b * S + qbase + 32 + l31) * 16 + h] = l1t;
  }
}

// ---------------- combine partials: Obuf = (O0 + O1) / (l0 + l1) ----------------
__global__ __launch_bounds__(256) void combine(const u16* __restrict__ Opart,
                                               const float* __restrict__ Lpart,
                                               u16* __restrict__ Obuf) {
  const int i = blockIdx.x * 256 + threadIdx.x;
  const int row = i >> 7;
  const int cw = (i & 127) * 8;
  const int h = cw >> 6;
  const float l = Lpart[(size_t)row * 16 + h] + Lpart[(size_t)4096 * 16 + (size_t)row * 16 + h];
  const float inv = 1.0f / l;
  const bf16x8 a = *(const bf16x8*)(Opart + (size_t)row * 1024 + cw);
  const bf16x8 bq = *(const bf16x8*)(Opart + (size_t)4096 * 1024 + (size_t)row * 1024 + cw);
  u16 out[8];
#pragma unroll
  for (int j = 0; j < 8; ++j) out[j] = f2bf(((float)a[j] + (float)bq[j]) * inv);
  *(uint4*)(Obuf + (size_t)row * 1024 + cw) = *(uint4*)out;
}

extern "C" void kernel_launch(void* const* d_in, const int* in_sizes, int n_in,
                              void* d_out, int out_size, void* d_ws, size_t ws_size,
                              hipStream_t stream) {
  const float* x  = (const float*)d_in[0];
  const float* WQ = (const float*)d_in[1];
  const float* WK = (const float*)d_in[2];
  const float* WV = (const float*)d_in[3];
  const float* WO = (const float*)d_in[4];
  float* out = (float*)d_out;

  u16* xb    = (u16*)d_ws;                      // 4096*1024
  u16* WtQKV = xb + (size_t)4096 * 1024;        // 3072*1024
  u16* WtO   = WtQKV + (size_t)3072 * 1024;     // 1024*1024
  u16* QKV   = WtO + (size_t)1024 * 1024;       // 4096*3072
  u16* Obuf  = QKV + (size_t)4096 * 3072;       // 4096*1024
  u16* Vtg   = Obuf + (size_t)4096 * 1024;      // 2048*2048
  u16* Opart = Vtg + (size_t)2048 * 2048;       // 2 * 4096*1024 bf16
  float* Lpart = (float*)(Opart + (size_t)2 * 4096 * 1024);  // 2 * 4096*16 f32

  prep<<<dim3(32, 32, 5), 256, 0, stream>>>(x, xb, WQ, WK, WV, WO, WtQKV, WtO);

  gemm_bt<1, 1><<<dim3(32, 24), 256, 0, stream>>>(xb, WtQKV, QKV, Vtg, 4096, 3072, 1024);
  attn_kernel<<<dim3(16, 32), 256, 0, stream>>>(QKV, Vtg, Opart, Lpart);
  combine<<<2048, 256, 0, stream>>>(Opart, Lpart, Obuf);
  gemm_bt<0, 0><<<dim3(32, 8), 256, 0, stream>>>(Obuf, WtO, out, nullptr, 4096, 1024, 1024);
}